// Round 3
// baseline (1132.703 us; speedup 1.0000x reference)
//
#include <hip/hip_runtime.h>

// HeteroGNN forward (SAGE mean-aggr, two relations), MI355X.
//
// Round 3:
//  - XCD-partitioned CSR build: node space split into 8 partitions; block b
//    scans edge chunk b/8 and only touches cnt/nbr entries in partition b%8.
//    With round-robin blockIdx->XCD placement, all writes to a given nbr/cnt
//    line come from ONE XCD -> single writeback instead of per-4B sector
//    writebacks (round-2 scatter: 250 MB WRITE_SIZE for a 16 MB array).
//    Correct regardless of the actual block->XCD mapping (partitions are
//    disjoint, deterministic functions of node id).
//  - Register-W transform: W columns live in 128 VGPRs/lane (one coalesced
//    load per block), row staged in LDS and read via broadcast float4.
//    Replaces the LDS-throughput-bound round-2 transform.

#define EPB 16384   // edges per chunk in partitioned CSR-build kernels

// ---------------------------------------------------------------------------
// Phase A: partitioned count
// ---------------------------------------------------------------------------
__global__ void count_part_kernel(const int* __restrict__ src, const int* __restrict__ dst,
                                  int* __restrict__ cnt, int Nr, int nE,
                                  float invR, float invU)
{
    const int p  = blockIdx.x & 7;
    const int c  = blockIdx.x >> 3;
    const int e0 = c * EPB;
    const int e1 = min(e0 + EPB, nE);
    for (int e = e0 + threadIdx.x; e < e1; e += blockDim.x) {
        const int dr = dst[e];
        const int su = src[e];
        if (min(7, (int)(dr * invR)) == p) atomicAdd(&cnt[dr], 1);
        if (min(7, (int)(su * invU)) == p) atomicAdd(&cnt[Nr + su], 1);
    }
}

#define SCAN_BS 2048   // elements per block in scan (256 thr x 8)

__global__ void scan_block_kernel(const int* __restrict__ cnt, int* __restrict__ off,
                                  int* __restrict__ partial, int N)
{
    __shared__ int sdata[256];
    const int t = threadIdx.x;
    const long long base = (long long)blockIdx.x * SCAN_BS + (long long)t * 8;
    int v[8];
    int s = 0;
    #pragma unroll
    for (int k = 0; k < 8; ++k) {
        long long i = base + k;
        v[k] = (i < N) ? cnt[i] : 0;
        s += v[k];
    }
    sdata[t] = s;
    __syncthreads();
    for (int d = 1; d < 256; d <<= 1) {
        int val = (t >= d) ? sdata[t - d] : 0;
        __syncthreads();
        if (t >= d) sdata[t] += val;
        __syncthreads();
    }
    if (t == 255) partial[blockIdx.x] = sdata[255];
    int run = sdata[t] - s;   // exclusive prefix for this thread's chunk
    #pragma unroll
    for (int k = 0; k < 8; ++k) {
        long long i = base + k;
        if (i < N) off[i] = run;
        run += v[k];
    }
}

__global__ void scan_partials_kernel(int* __restrict__ partial, int nb)
{
    __shared__ int sdata[256];
    const int t = threadIdx.x;
    int v = (t < nb) ? partial[t] : 0;
    sdata[t] = v;
    __syncthreads();
    for (int d = 1; d < 256; d <<= 1) {
        int val = (t >= d) ? sdata[t - d] : 0;
        __syncthreads();
        if (t >= d) sdata[t] += val;
        __syncthreads();
    }
    if (t < nb) partial[t] = sdata[t] - v;   // exclusive
}

__global__ void scan_addback_kernel(int* __restrict__ off, const int* __restrict__ partial,
                                    int N, int total)
{
    long long i = (long long)blockIdx.x * blockDim.x + threadIdx.x;
    if (i < N) off[i] += partial[i / SCAN_BS];
    if (i == 0) off[N] = total;
}

// ---------------------------------------------------------------------------
// Phase A: partitioned bucket scatter (XCD-local writes)
// ---------------------------------------------------------------------------
__global__ void scatter_part_kernel(const int* __restrict__ src, const int* __restrict__ dst,
                                    const int* __restrict__ off, int* __restrict__ cnt,
                                    int* __restrict__ nbr, int Nr, int nE,
                                    float invR, float invU)
{
    const int p  = blockIdx.x & 7;
    const int c  = blockIdx.x >> 3;
    const int e0 = c * EPB;
    const int e1 = min(e0 + EPB, nE);
    for (int e = e0 + threadIdx.x; e < e1; e += blockDim.x) {
        const int dr = dst[e];
        const int su = src[e];
        if (min(7, (int)(dr * invR)) == p) {
            int pos = off[dr] + atomicSub(&cnt[dr], 1) - 1;
            nbr[pos] = su;
        }
        if (min(7, (int)(su * invU)) == p) {
            int pos = off[Nr + su] + atomicSub(&cnt[Nr + su], 1) - 1;
            nbr[pos] = dr;
        }
    }
}

// ---------------------------------------------------------------------------
// Phase B: atomic-free gather + mean.  16 lanes per node; lane owns 4 feats.
// ---------------------------------------------------------------------------
__device__ __forceinline__ void f4add(float4& a, const float4 v) {
    a.x += v.x; a.y += v.y; a.z += v.z; a.w += v.w;
}

__global__ void gather_mean_kernel(const float* __restrict__ x,
                                   const int* __restrict__ off,
                                   const int* __restrict__ nbr,
                                   float* __restrict__ agg, int N)
{
    const int tid  = blockIdx.x * blockDim.x + threadIdx.x;
    const int g    = tid >> 4;
    if (g >= N) return;
    const int lane = tid & 15;
    const int c    = lane << 2;

    const int beg = off[g];
    const int end = off[g + 1];

    float4 a0 = {0,0,0,0}, a1 = {0,0,0,0}, a2 = {0,0,0,0}, a3 = {0,0,0,0};
    int j = beg;
    for (; j + 4 <= end; j += 4) {
        const int s0 = nbr[j], s1 = nbr[j+1], s2 = nbr[j+2], s3 = nbr[j+3];
        f4add(a0, *reinterpret_cast<const float4*>(x + ((long long)s0 << 6) + c));
        f4add(a1, *reinterpret_cast<const float4*>(x + ((long long)s1 << 6) + c));
        f4add(a2, *reinterpret_cast<const float4*>(x + ((long long)s2 << 6) + c));
        f4add(a3, *reinterpret_cast<const float4*>(x + ((long long)s3 << 6) + c));
    }
    for (; j < end; ++j) {
        f4add(a0, *reinterpret_cast<const float4*>(x + ((long long)nbr[j] << 6) + c));
    }
    f4add(a0, a1); f4add(a2, a3); f4add(a0, a2);

    const float inv = 1.0f / (float)max(end - beg, 1);
    float4 r; r.x = a0.x * inv; r.y = a0.y * inv; r.z = a0.z * inv; r.w = a0.w * inv;
    *reinterpret_cast<float4*>(agg + ((long long)g << 6) + c) = r;
}

// ---------------------------------------------------------------------------
// Phase C: register-W row transform. Lane h holds column h of Wl and Wr in
// VGPRs; the row is staged in per-wave LDS and read via broadcast float4.
// out = relu( agg @ Wl + bl + xroot @ Wr ).  In-place safe (row staged
// before overwrite).
// ---------------------------------------------------------------------------
__global__ void transform_reg_kernel(const float* __restrict__ agg,
                                     const float* __restrict__ xroot,
                                     const float* __restrict__ Wl,
                                     const float* __restrict__ bl,
                                     const float* __restrict__ Wr,
                                     float* __restrict__ out, int N)
{
    __shared__ float srow[4][64];
    __shared__ float sx[4][64];
    const int t = threadIdx.x;
    const int w = t >> 6;     // wave id, owns one row per iteration
    const int h = t & 63;     // output feature / lane

    float wl[64], wr[64];
    #pragma unroll
    for (int d = 0; d < 64; ++d) {
        wl[d] = Wl[d * 64 + h];      // coalesced across lanes per d
        wr[d] = Wr[d * 64 + h];
    }
    const float bias = bl[h];

    for (long long r0 = (long long)blockIdx.x * 4; r0 < N; r0 += (long long)gridDim.x * 4) {
        const long long r = r0 + w;
        float v = 0.0f, xv = 0.0f;
        if (r < N) {
            v  = agg[(r << 6) + h];
            xv = xroot[(r << 6) + h];
        }
        __syncthreads();               // previous iteration's reads complete
        srow[w][h] = v;
        sx[w][h]   = xv;
        __syncthreads();
        if (r < N) {
            float acc = bias;
            #pragma unroll
            for (int d0 = 0; d0 < 64; d0 += 4) {
                const float4 a  = *reinterpret_cast<const float4*>(&srow[w][d0]);
                const float4 xx = *reinterpret_cast<const float4*>(&sx[w][d0]);
                acc += a.x  * wl[d0]     + a.y  * wl[d0 + 1]
                     + a.z  * wl[d0 + 2] + a.w  * wl[d0 + 3];
                acc += xx.x * wr[d0]     + xx.y * wr[d0 + 1]
                     + xx.z * wr[d0 + 2] + xx.w * wr[d0 + 3];
            }
            out[(r << 6) + h] = fmaxf(acc, 0.0f);
        }
    }
}

// ---------------------------------------------------------------------------
// Fallback (round-1) kernels, used only if ws_size is too small for CSR.
// ---------------------------------------------------------------------------
__global__ void edge_scatter_kernel(
    const float* __restrict__ xu, const float* __restrict__ xr,
    const int* __restrict__ src, const int* __restrict__ dst,
    float* __restrict__ agg_r, float* __restrict__ agg_u,
    float* __restrict__ deg_r, float* __restrict__ deg_u,
    int nE)
{
    int tid  = blockIdx.x * blockDim.x + threadIdx.x;
    int e    = tid >> 4;
    if (e >= nE) return;
    int lane = tid & 15;
    int su = src[e];
    int dr = dst[e];
    if (lane == 0) {
        atomicAdd(&deg_r[dr], 1.0f);
        atomicAdd(&deg_u[su], 1.0f);
    }
    const float4 a = *reinterpret_cast<const float4*>(xu + ((long long)su << 6) + (lane << 2));
    const float4 b = *reinterpret_cast<const float4*>(xr + ((long long)dr << 6) + (lane << 2));
    float* pr = agg_r + ((long long)dr << 6) + (lane << 2);
    float* pu = agg_u + ((long long)su << 6) + (lane << 2);
    atomicAdd(pr + 0, a.x); atomicAdd(pr + 1, a.y);
    atomicAdd(pr + 2, a.z); atomicAdd(pr + 3, a.w);
    atomicAdd(pu + 0, b.x); atomicAdd(pu + 1, b.y);
    atomicAdd(pu + 2, b.z); atomicAdd(pu + 3, b.w);
}

__global__ void transform_kernel(
    const float* __restrict__ agg, const float* __restrict__ deg,
    const float* __restrict__ xroot,
    const float* __restrict__ Wl, const float* __restrict__ bl,
    const float* __restrict__ Wr,
    float* __restrict__ out, int N)
{
    __shared__ float sWl[64 * 64];
    __shared__ float sWr[64 * 64];
    __shared__ float sb[64];
    __shared__ float sAgg[4][64];
    __shared__ float sX[4][64];

    const int t = threadIdx.x;
    for (int i = t; i < 64 * 64; i += 256) {
        sWl[i] = Wl[i];
        sWr[i] = Wr[i];
    }
    if (t < 64) sb[t] = bl[t];
    __syncthreads();

    const int rg = t >> 6;
    const int h  = t & 63;

    for (long long r0 = (long long)blockIdx.x * 4; r0 < N; r0 += (long long)gridDim.x * 4) {
        const long long r = r0 + rg;
        if (r < N) {
            float inv = 1.0f / fmaxf(deg[r], 1.0f);
            sAgg[rg][h] = agg[(r << 6) + h] * inv;
            sX[rg][h]   = xroot[(r << 6) + h];
        }
        __syncthreads();
        if (r < N) {
            float acc = sb[h];
            #pragma unroll
            for (int d = 0; d < 64; ++d) {
                acc += sAgg[rg][d] * sWl[d * 64 + h] + sX[rg][d] * sWr[d * 64 + h];
            }
            out[(r << 6) + h] = fmaxf(acc, 0.0f);
        }
        __syncthreads();
    }
}

extern "C" void kernel_launch(void* const* d_in, const int* in_sizes, int n_in,
                              void* d_out, int out_size, void* d_ws, size_t ws_size,
                              hipStream_t stream)
{
    const float* xu    = (const float*)d_in[0];
    const float* xr    = (const float*)d_in[1];
    const int*   src   = (const int*)  d_in[2];
    const int*   dst   = (const int*)  d_in[3];
    const float* Wl_ur = (const float*)d_in[4];
    const float* bl_ur = (const float*)d_in[5];
    const float* Wr_ur = (const float*)d_in[6];
    const float* Wl_ru = (const float*)d_in[7];
    const float* bl_ru = (const float*)d_in[8];
    const float* Wr_ru = (const float*)d_in[9];

    const int Nu = in_sizes[0] / 64;
    const int Nr = in_sizes[1] / 64;
    const int nE = in_sizes[2];
    const int NN = Nr + Nu;

    float* out   = (float*)d_out;
    float* agg_r = out;                        // [Nr,64]
    float* agg_u = out + (long long)Nr * 64;   // [Nu,64]

    // ---- workspace layout (ints) ----
    int* cnt     = (int*)d_ws;                  // [NN]
    int* off     = cnt + NN;                    // [NN+1]
    int* partial = off + NN + 1;                // [256]
    int* nbr     = partial + 256;               // [2E]
    const size_t need = ((size_t)NN + (size_t)NN + 1 + 256 + 2ull * nE) * sizeof(int);

    if (ws_size >= need) {
        // ---------------- CSR path ----------------
        hipMemsetAsync(cnt, 0, (size_t)NN * sizeof(int), stream);

        const float invR = 8.0f / (float)Nr;
        const float invU = 8.0f / (float)Nu;
        const int nChunks = (nE + EPB - 1) / EPB;
        const int grid    = nChunks * 8;

        count_part_kernel<<<grid, 256, 0, stream>>>(src, dst, cnt, Nr, nE, invR, invU);

        const int nScanBlocks = (NN + SCAN_BS - 1) / SCAN_BS;   // <= 256
        scan_block_kernel<<<nScanBlocks, 256, 0, stream>>>(cnt, off, partial, NN);
        scan_partials_kernel<<<1, 256, 0, stream>>>(partial, nScanBlocks);
        scan_addback_kernel<<<(NN + 255) / 256, 256, 0, stream>>>(off, partial, NN, 2 * nE);

        scatter_part_kernel<<<grid, 256, 0, stream>>>(src, dst, off, cnt, nbr, Nr, nE, invR, invU);

        // gathers (mean fused in; writes every output row)
        {
            const long long tr = (long long)Nr * 16;
            gather_mean_kernel<<<(int)((tr + 255) / 256), 256, 0, stream>>>(
                xu, off, nbr, agg_r, Nr);
            const long long tu = (long long)Nu * 16;
            gather_mean_kernel<<<(int)((tu + 255) / 256), 256, 0, stream>>>(
                xr, off + Nr, nbr, agg_u, Nu);
        }

        transform_reg_kernel<<<512, 256, 0, stream>>>(
            agg_r, xr, Wl_ur, bl_ur, Wr_ur, agg_r, Nr);
        transform_reg_kernel<<<512, 256, 0, stream>>>(
            agg_u, xu, Wl_ru, bl_ru, Wr_ru, agg_u, Nu);
    } else {
        // ---------------- fallback: atomic path ----------------
        float* deg_r = (float*)d_ws;
        float* deg_u = deg_r + Nr;
        hipMemsetAsync(d_out, 0, (size_t)out_size * sizeof(float), stream);
        hipMemsetAsync(d_ws, 0, (size_t)NN * sizeof(float), stream);

        const long long total = (long long)nE * 16;
        edge_scatter_kernel<<<(int)((total + 255) / 256), 256, 0, stream>>>(
            xu, xr, src, dst, agg_r, agg_u, deg_r, deg_u, nE);

        transform_kernel<<<2048, 256, 0, stream>>>(
            agg_r, deg_r, xr, Wl_ur, bl_ur, Wr_ur, agg_r, Nr);
        transform_kernel<<<2048, 256, 0, stream>>>(
            agg_u, deg_u, xu, Wl_ru, bl_ru, Wr_ru, agg_u, Nu);
    }
}